// Round 16
// baseline (208.600 us; speedup 1.0000x reference)
//
#include <hip/hip_runtime.h>
#include <math.h>

#define NB 4
#define C_IN 256
#define CKC 64
#define HWSZ 4096   // 64*64
#define K2 25
#define NOC2 40     // 33 output chans padded to 40 (8 groups x 5)

// workspace layout (float offsets)
#define WS_CX    0                               // cx region DEAD (fusion); first 16384 floats host wcT
#define WS_OFF   (WS_CX + NB*CKC*HWSZ)          // 1048576
#define WS_MASK  (WS_OFF + NB*8*HWSZ)           // +131072
#define WS_WT    (WS_MASK + NB*K2*HWSZ)         // +409600

#define NWT (CKC * 9 * NOC2)    // 23040
#define NWC (C_IN * CKC)        // 16384

// LDS-only barrier (r15: null vs __syncthreads, kept -- equal-best total).
#define BARRIER_LDS() do { \
    asm volatile("s_waitcnt lgkmcnt(0)" ::: "memory"); \
    __builtin_amdgcn_s_barrier(); \
  } while (0)

// ---------------- Kernel D: weight prep ----------------
// wT[c][tap][oc(40)] for the 3x3 convs; wcT[c][ck] for the compressor.
__global__ void k_wt(const float* __restrict__ wk, const float* __restrict__ wo,
                     const float* __restrict__ wc,
                     float* __restrict__ wT, float* __restrict__ wcT) {
  int i = blockIdx.x * 256 + threadIdx.x;
  if (i < NWT) {
    int oc = i % NOC2;
    int r = i / NOC2;        // r = c*9 + tap
    int tap = r % 9, c = r / 9;
    float v = 0.f;
    if (oc < 8)       v = wo[(oc * CKC + c) * 9 + tap];
    else if (oc < 33) v = wk[((oc - 8) * CKC + c) * 9 + tap];
    wT[i] = v;
  } else {
    int j = i - NWT;
    if (j < NWC) {
      int c = j >> 6, ck = j & 63;
      wcT[j] = wc[ck * C_IN + c];
    }
  }
}

// ---------------- Kernel B (v11): FUSED compress+conv+softmax ----------
// grid (128,4) x 1024 thr: block = one 8x4 tile -> 512 blocks = 2 blocks/CU
// = 32 waves/CU (was 16: grid 256 capped occupancy at 1 block/CU).
// r12 proved wave-doubling = -15% on this kernel; this is the second
// doubling, via BLOCK-level overlap (one block's staging/barriers hide
// under the other's FMA). Costs: halo redundancy 1.69->1.875x (+11%
// compress FLOPs); conv uses half-wave (32px/block) -- same per-thread
// chain, unchanged per-CU conv wall with 2 resident blocks.
// Geometry: halo 6 rows x 10 cols (60 pos); staging [64c][6x12] from x0-2
// (f2-aligned, dst=2e); one position per lane (p<60); s_tile [ck][64]
// stride-10 rows; s_res [40][32]. Same dbuf/T14/ch-split skeleton as v8.
__global__ __launch_bounds__(1024) void k_cs(const float* __restrict__ x,
    const float* __restrict__ wcT, const float* __restrict__ bc,
    const float* __restrict__ wT, const float* __restrict__ bk, const float* __restrict__ bo,
    float* __restrict__ offb, float* __restrict__ maskb) {
  __attribute__((aligned(16))) __shared__ float s_mem[9216];  // 36864B union
  // compress: s_A = s_mem[0..4607], s_B = s_mem[4608..9215]  (64c x 72)
  // conv:     s_tile[64][64] = s_mem[0..4095]  (60 pos + pad, stride-10 rows)
  // epilogue: s_res[40*32]   = s_mem[0..1279]
  float* s_tile = s_mem;
  float* s_res  = s_mem;

  int t = threadIdx.x;
  int n = blockIdx.y;
  int tile = blockIdx.x;               // 0..127
  int x0 = (tile & 7) * 8, y0 = (tile >> 3) * 4;
  const float* xn = x + (size_t)n * (C_IN * HWSZ);

  int p = t & 63;                                   // lane
  int w = t >> 6;                                   // wave 0..15
  int g = __builtin_amdgcn_readfirstlane(w & 7);    // ck/oc-group, wave-uniform
  int ch = __builtin_amdgcn_readfirstlane(w >> 3);  // c-half, wave-uniform

  // ---- staging descriptors (full 64-c chunk = 2304 f2 = 64c x 36) ----
  // e = t + it*1024; c = e/36, rem = e%36 (6 rows x 6 f2); dst = 2e.
  int srcOff[3];
  unsigned vbits = 0, wbits = 0;
  #pragma unroll
  for (int it = 0; it < 3; it++) {
    int e = t + it * 1024;
    int c = e / 36;
    int rem = e - c * 36;
    int row = rem / 6, pr = rem - row * 6;
    int gy = y0 - 1 + row;
    int gc0 = x0 - 2 + pr * 2;
    bool wr = (e < 2304);
    bool ok = wr & ((unsigned)gy < 64u) & ((unsigned)gc0 < 63u);  // pair fully in [0,63]
    srcOff[it] = ok ? (c * HWSZ + gy * 64 + gc0) : 0;
    vbits |= (ok ? 1u : 0u) << it;
    wbits |= (wr ? 1u : 0u) << it;
  }

  // position ownership: lane p owns halo position p (p<60); clamped else.
  int pos = (p < 60) ? p : 59;
  int prow = pos / 10, pcol = pos - prow * 10;
  int paddr = prow * 12 + pcol + 1;    // staged addr (staging starts x0-2)
  bool pval = (p < 60);
  float a[8];
  #pragma unroll
  for (int i = 0; i < 8; i++) a[i] = (ch == 0) ? bc[g * 8 + i] : 0.f;

  // prefetch chunk 0; prologue: A <- chunk0, issue chunk1
  float2 rv[3];
  #pragma unroll
  for (int it = 0; it < 3; it++) rv[it] = *(const float2*)(xn + srcOff[it]);

  float* sA = s_mem;
  float* sB = s_mem + 4608;
  #pragma unroll
  for (int it = 0; it < 3; it++)
    if (wbits & (1u << it))
      *(float2*)(&sA[2 * (t + it * 1024)]) =
          (vbits & (1u << it)) ? rv[it] : make_float2(0.f, 0.f);
  {
    const float* xb = xn + (size_t)64 * HWSZ;
    #pragma unroll
    for (int it = 0; it < 3; it++) rv[it] = *(const float2*)(xb + srcOff[it]);
  }
  BARRIER_LDS();

  for (int k = 0; k < 4; k++) {
    // stage next chunk into B (overlaps FMA of the active half)
    if (k < 3) {
      #pragma unroll
      for (int it = 0; it < 3; it++)
        if (wbits & (1u << it))
          *(float2*)(&sB[2 * (t + it * 1024)]) =
              (vbits & (1u << it)) ? rv[it] : make_float2(0.f, 0.f);
    }
    // issue chunk k+2 loads; latency hides under FMA phase
    if (k < 2) {
      const float* xb = xn + (size_t)(k + 2) * 64 * HWSZ;
      #pragma unroll
      for (int it = 0; it < 3; it++) rv[it] = *(const float2*)(xb + srcOff[it]);
    }
    // FMA over A by the matching c-half (wave-uniform branch)
    if ((k >> 1) == ch) {
      const float* wbase = wcT + (k * 64) * 64 + g * 8;
      #pragma unroll 4
      for (int c = 0; c < 64; c++) {
        float v = sA[c * 72 + paddr];
        const float* wp = wbase + c * 64;
        #pragma unroll
        for (int i = 0; i < 8; i++) a[i] += v * wp[i];
      }
    }
    BARRIER_LDS();
    float* tmp = sA; sA = sB; sB = tmp;
  }

  // combine c-half partials into s_tile [ck][64] (aliases dead staging).
  // ch1 writes; barrier; ch0 adds (carries bias).
  if (ch == 1 && pval) {
    #pragma unroll
    for (int i = 0; i < 8; i++) s_tile[(g * 8 + i) * 64 + pos] = a[i];
  }
  BARRIER_LDS();
  if (ch == 0 && pval) {
    #pragma unroll
    for (int i = 0; i < 8; i++) {
      int idx = (g * 8 + i) * 64 + pos;
      s_tile[idx] = s_tile[idx] + a[i];
    }
  }
  BARRIER_LDS();

  // ---- conv part: wave (g, ch) covers c in [ch*32, ch*32+32) ----
  // 32 output px (8x4): lanes 0..31 active; halo rows stride 10.
  int px = p & 7, py = (p >> 3) & 3;
  bool cact = (p < 32);
  float acc[5];
  #pragma unroll
  for (int j = 0; j < 5; j++) acc[j] = 0.f;
  const float* wg = wT + g * 5;
  const float* tl0 = s_tile + py * 10 + px;
  int cb = ch * 32;

#define LOADWIN(dst, cidx)                                   \
  {                                                          \
    const float* tlc = tl0 + (cidx) * 64;                    \
    _Pragma("unroll")                                        \
    for (int tap = 0; tap < 9; tap++) {                      \
      int dy = tap / 3, dx = tap % 3;                        \
      dst[tap] = tlc[dy * 10 + dx];                          \
    }                                                        \
  }
#define FMAWIN(src, cidx)                                    \
  {                                                          \
    const float* wc9 = wg + (cidx) * 9 * NOC2;               \
    _Pragma("unroll")                                        \
    for (int tap = 0; tap < 9; tap++) {                      \
      float v = src[tap];                                    \
      const float* wp = wc9 + tap * NOC2;                    \
      _Pragma("unroll")                                      \
      for (int j = 0; j < 5; j++) acc[j] += v * wp[j];       \
    }                                                        \
  }

  if (cact) {
    float wa[9], wbuf[9];
    LOADWIN(wa, cb + 0)
    LOADWIN(wbuf, cb + 1)
    #pragma unroll 1
    for (int c = 0; c < 32; c += 2) {
      FMAWIN(wa, cb + c)
      if (c + 2 < 32) LOADWIN(wa, cb + c + 2)
      FMAWIN(wbuf, cb + c + 1)
      if (c + 3 < 32) LOADWIN(wbuf, cb + c + 3)
    }
  }
#undef LOADWIN
#undef FMAWIN

  // s_res [40][32] aliases s_tile: reads done -> ch0 writes, ch1 adds
  BARRIER_LDS();
  if (ch == 0 && cact) {
    #pragma unroll
    for (int j = 0; j < 5; j++) s_res[(g * 5 + j) * 32 + p] = acc[j];
  }
  BARRIER_LDS();
  if (ch == 1 && cact) {
    #pragma unroll
    for (int j = 0; j < 5; j++) s_res[(g * 5 + j) * 32 + p] += acc[j];
  }
  BARRIER_LDS();

  int hw = (y0 + py) * 64 + x0 + px;
  // offsets: 8 channels; ch0 wave g, lanes 0..31 write oc = g
  if (ch == 0 && cact)
    offb[(n * 8 + g) * HWSZ + hw] = s_res[g * 32 + p] + bo[g];
  // softmax over 25 kernel positions: threads 0..31, one pixel per lane
  if (t < 32) {
    float m[25], mx = -1e30f;
    #pragma unroll
    for (int k = 0; k < 25; k++) { m[k] = s_res[(8 + k) * 32 + t] + bk[k]; mx = fmaxf(mx, m[k]); }
    float s = 0.f;
    #pragma unroll
    for (int k = 0; k < 25; k++) { m[k] = __expf(m[k] - mx); s += m[k]; }
    float inv = 1.f / s;
    int hw0 = (y0 + ((t >> 3) & 3)) * 64 + x0 + (t & 7);
    #pragma unroll
    for (int k = 0; k < 25; k++) maskb[(n * 25 + k) * HWSZ + hw0] = m[k] * inv;
  }
}

// ---------------- Kernel C (v7): main CARAFE reassembly ----------------
// FROZEN structure (r5-verified 45.1us + r15 BARRIER_LDS, null-neutral).
__global__ __launch_bounds__(256, 4) void k_carafe(const float* __restrict__ x,
    const float* __restrict__ offb, const float* __restrict__ maskb,
    float* __restrict__ out) {
  __attribute__((aligned(16))) __shared__ float s_patch[32 * 202]; // 25856B; aliased as s_out [32][130]
  __attribute__((aligned(16))) __shared__ float s_kern[32 * 25 * 4]; // 12800B
  int t = threadIdx.x;
  int b = blockIdx.x;
  int n = b >> 8;
  int r = b & 255;
  int half = r & 1;
  int wq = (r >> 1) & 3;
  int aa = r >> 3;
  int a = aa + (aa & 16);                 // h base: bit4 == 0
  int yout = (a & 15) * 8 + wq * 2 + ((a >> 5) & 1);
  int w0 = wq * 16;
  int cbase = n * C_IN + half * 128;

  // ---- hoisted float2 staging descriptors (computed ONCE) ----
  int srcOff[13];          // channel-plane-relative src offset (pair base)
  int dstOff[13];          // LDS float index (8B aligned)
  unsigned vbits = 0;      // data-valid (in-bounds) mask
  unsigned wbits = 0;      // write-enable (e < 3200) mask
  #pragma unroll
  for (int it = 0; it < 13; it++) {
    int e = t + it * 256;
    int c = e / 100;
    int rem = e - c * 100;
    int rg = rem / 10;
    int c2 = rem - rg * 10;
    int row = (rg < 5) ? (a - 2 + rg) : (a + 9 + rg);
    int gc0 = w0 - 2 + c2 * 2;
    bool wr = (e < 3200);
    bool ok = wr & ((unsigned)row < 64u) & ((unsigned)gc0 < 64u);
    srcOff[it] = ok ? (c * HWSZ + row * 64 + gc0) : 0;
    dstOff[it] = wr ? 2 * (e + c) : 0;
    vbits |= (ok ? 1u : 0u) << it;
    wbits |= (wr ? 1u : 0u) << it;
  }

  // prefetch chunk 0 into registers (flies during phase 1)
  float2 rv[13];
  {
    const float* xn = x + (size_t)cbase * HWSZ;
    #pragma unroll
    for (int it = 0; it < 13; it++) rv[it] = *(const float2*)(xn + srcOff[it]);
  }

  // Phase 1: per-(pos,u) 25 resampled kernel weights -> LDS [p][tap][u]
  if (t < 128) {
    int p = t >> 2, u = t & 3;
    int hb = p >> 4, wl = p & 15;
    int h = a + hb * 16;
    int wcol = w0 + wl;
    float ox = offb[(n * 8 + u) * HWSZ + h * 64 + wcol];
    float oy = offb[(n * 8 + 4 + u) * HWSZ + h * 64 + wcol];
    float gx = fminf(fmaxf((float)wcol + ox, 0.f), 63.f);
    float gy = fminf(fmaxf((float)h + oy, 0.f), 63.f);
    float fx0 = floorf(gx), fy0 = floorf(gy);
    int x0 = (int)fx0, y0 = (int)fy0;
    float fx = gx - fx0, fy = gy - fy0;
    int x1 = min(x0 + 1, 63), y1 = min(y0 + 1, 63);
    float w11 = fx * fy;
    float w10 = fy - w11, w01 = fx - w11, w00 = 1.f - fx - fy + w11;
    const float* mb = maskb + n * (K2 * HWSZ);
    int i00 = y0 * 64 + x0, i01 = y0 * 64 + x1;
    int i10 = y1 * 64 + x0, i11 = y1 * 64 + x1;
    #pragma unroll 5
    for (int k = 0; k < 25; k++) {
      const float* mk = mb + k * HWSZ;
      float v = w00 * mk[i00] + w01 * mk[i01] + w10 * mk[i10] + w11 * mk[i11];
      s_kern[(p * 25 + k) * 4 + u] = v;
    }
  }

  int cl = t & 31, g = t >> 5;            // channel lane 0..31, pos-group 0..7
  int hb = g >> 2, wl0 = (g & 3) * 4;     // each group: 4 consecutive wl in one hb
  float* s_out = s_patch;                 // alias: [32][130] = 16640B <= 25856B

  for (int cc = 0; cc < 4; cc++) {
    BARRIER_LDS();   // covers phase-1 (first iter) and staging-vs-store alias (later)
    // stage x patch from prefetched registers: 32 c x 10 rows x 20 cols
    #pragma unroll
    for (int it = 0; it < 13; it++) {
      if (wbits & (1u << it)) {
        float2 v = (vbits & (1u << it)) ? rv[it] : make_float2(0.f, 0.f);
        *(float2*)(&s_patch[dstOff[it]]) = v;   // ds_write_b64
      }
    }
    BARRIER_LDS();
    // issue next chunk's loads NOW; latency hides under compute+store below
    if (cc < 3) {
      const float* xn = x + (size_t)(cbase + (cc + 1) * 32) * HWSZ;
      #pragma unroll
      for (int it = 0; it < 13; it++) rv[it] = *(const float2*)(xn + srcOff[it]);
    }
    // compute: thread (cl, g) -> 4 positions x 4 u; register row-cache over dy
    float acc[4][4];
    #pragma unroll
    for (int i = 0; i < 4; i++)
      acc[i][0] = acc[i][1] = acc[i][2] = acc[i][3] = 0.f;
    const float* pc = s_patch + cl * 202 + hb * 100 + wl0;
    #pragma unroll
    for (int dy = 0; dy < 5; dy++) {
      float r8[8];
      #pragma unroll
      for (int j = 0; j < 8; j++) r8[j] = pc[dy * 20 + j];
      #pragma unroll
      for (int pr = 0; pr < 4; pr++) {
        const float4* kp = (const float4*)(s_kern + (((g * 4 + pr) * 25) + dy * 5) * 4);
        #pragma unroll
        for (int dx = 0; dx < 5; dx++) {
          float f = r8[pr + dx];
          float4 k4 = kp[dx];
          acc[pr][0] += f * k4.x;
          acc[pr][1] += f * k4.y;
          acc[pr][2] += f * k4.z;
          acc[pr][3] += f * k4.w;
        }
      }
    }
    BARRIER_LDS();
    // transpose through LDS: s_out[c][x] stride 130, x = wl*8 + u*2 + hb
    #pragma unroll
    for (int pr = 0; pr < 4; pr++) {
      int wl = wl0 + pr;
      #pragma unroll
      for (int u = 0; u < 4; u++) {
        int xo = wl * 8 + u * 2 + hb;
        s_out[cl * 130 + xo] = acc[pr][u];
      }
    }
    BARRIER_LDS();
    // coalesced store: 32 channel-rows x 128 x at fixed yout
    float* obase = out + ((size_t)(cbase + cc * 32) * 128 + yout) * 128;
    #pragma unroll
    for (int it = 0; it < 4; it++) {
      int q2 = t + it * 256;
      int rowc = q2 >> 5;       // 0..31 (channel within chunk)
      int col4 = q2 & 31;       // float4 index within row
      const float* sp = s_out + rowc * 130 + col4 * 4;
      float4 v = make_float4(sp[0], sp[1], sp[2], sp[3]);
      *(float4*)(obase + (size_t)rowc * (128 * 128) + col4 * 4) = v;
    }
  }
}

extern "C" void kernel_launch(void* const* d_in, const int* in_sizes, int n_in,
                              void* d_out, int out_size, void* d_ws, size_t ws_size,
                              hipStream_t stream) {
  const float* x      = (const float*)d_in[0];
  const float* w_comp = (const float*)d_in[1];
  const float* b_comp = (const float*)d_in[2];
  const float* w_ker  = (const float*)d_in[3];
  const float* b_ker  = (const float*)d_in[4];
  const float* w_off  = (const float*)d_in[5];
  const float* b_off  = (const float*)d_in[6];
  float* out = (float*)d_out;
  float* ws = (float*)d_ws;
  float* offb  = ws + WS_OFF;
  float* maskb = ws + WS_MASK;
  float* wT    = ws + WS_WT;
  float* wcT   = ws + WS_CX;   // cx region is dead post-fusion; wcT lives there

  hipLaunchKernelGGL(k_wt, dim3((NWT + NWC + 255) / 256), dim3(256), 0, stream,
                     w_ker, w_off, w_comp, wT, wcT);
  hipLaunchKernelGGL(k_cs, dim3(128, 4), dim3(1024), 0, stream,
                     x, wcT, b_comp, wT, b_ker, b_off, offb, maskb);
  hipLaunchKernelGGL(k_carafe, dim3(1024), dim3(256), 0, stream, x, offb, maskb, out);
}